// Round 14
// baseline (1372.628 us; speedup 1.0000x reference)
//
#include <hip/hip_runtime.h>
#include <hip/hip_bf16.h>

typedef __attribute__((ext_vector_type(4))) float f32x4;
typedef __attribute__((ext_vector_type(8))) short s16x8;   // 8 bf16 (4 VGPR) mfma frag
typedef __attribute__((ext_vector_type(4))) short s16x4;   // 4 bf16 (8B)
typedef __attribute__((ext_vector_type(4))) unsigned u32x4; // 16B load/store tuple

#define BATCH 256
#define SEQL  512
#define DIN   256
#define DH    512
#define NG    2048   // 4*DH, gate-interleaved: n = 4*unit + gate (0=g,1=i,2=f,3=o)
#define KTOT  768
#define NKT   24     // 8 x-kt (3 MFMA each) + 16 h-kt (2 MFMA each)
#define NCLS  1024
#define NTH   512
#define ROWS  16
#define COLS  128
#define XSTR  264    // x-plane row stride (shorts): 132 words == 4 mod 32
#define HSTR  520    // h-plane row stride (shorts): 260 words == 4 mod 32

// bf16 RNE from f32, bit-twiddle (finite inputs)
__device__ __forceinline__ short bf16_rne(float a) {
    union { float f; unsigned u; } ua; ua.f = a;
    unsigned r = (ua.u + 0x7FFFu + ((ua.u >> 16) & 1u)) >> 16;
    return (short)r;
}
__device__ __forceinline__ float bf16_to_f32(short b) {
    union { unsigned u; float f; } v; v.u = ((unsigned)(unsigned short)b) << 16;
    return v.f;
}
__device__ __forceinline__ float fast_sigmoid(float z) {
    return __builtin_amdgcn_rcpf(1.0f + __expf(-z));
}
__device__ __forceinline__ float fast_tanh(float z) {
    return 1.0f - 2.0f * __builtin_amdgcn_rcpf(__expf(2.0f * z) + 1.0f);
}

// ---------------------------------------------------------------------------
// Pack W into hi/lo bf16 planes [n][k]. Pack biases. Zero h buffers + bar.
// ---------------------------------------------------------------------------
__global__ void pack_kernel(const float* __restrict__ Wgx, const float* __restrict__ Wgh,
                            const float* __restrict__ Wix, const float* __restrict__ Wih,
                            const float* __restrict__ Wfx, const float* __restrict__ Wfh,
                            const float* __restrict__ Wox, const float* __restrict__ Woh,
                            const float* __restrict__ bg,  const float* __restrict__ bi,
                            const float* __restrict__ bf,  const float* __restrict__ bo,
                            short* __restrict__ Wb_hi, short* __restrict__ Wb_lo,
                            float* __restrict__ bp, unsigned* __restrict__ hp,
                            unsigned* __restrict__ bar)
{
    int idx = blockIdx.x * blockDim.x + threadIdx.x;
    if (idx < KTOT * NG) {
        int n = idx / KTOT;
        int k = idx - n * KTOT;
        int unit = n >> 2;
        int gate = n & 3;
        float v;
        if (k < DIN) {
            const float* src = (gate == 0) ? Wgx : (gate == 1) ? Wix : (gate == 2) ? Wfx : Wox;
            v = src[k * DH + unit];
        } else {
            const float* src = (gate == 0) ? Wgh : (gate == 1) ? Wih : (gate == 2) ? Wfh : Woh;
            v = src[(k - DIN) * DH + unit];
        }
        short hi = bf16_rne(v);
        short lo = bf16_rne(v - bf16_to_f32(hi));
        Wb_hi[idx] = hi;
        Wb_lo[idx] = lo;
    }
    if (idx < NG) {
        int unit = idx >> 2;
        int gate = idx & 3;
        const float* bsrc = (gate == 0) ? bg : (gate == 1) ? bi : (gate == 2) ? bf : bo;
        bp[idx] = bsrc[unit];
    }
    if (idx < (2 * BATCH * DH) / 2) hp[idx] = 0u;
    if (idx < 1024) bar[idx] = 0u;
}

// ---------------------------------------------------------------------------
// Persistent MFMA LSTM — r9 structure (proven), h-datapath slimmed:
// h is PLAIN bf16 (x stays split hi/lo, W split hi/lo pinned in 192 regs).
// Per wave/step: 8 x-kt x 3 MFMA + 16 h-kt x 2 MFMA = 56 MFMA, 32 b128 LDS
// reads. h staged: 2x global_load_dwordx4 (sc0) + 2x b128 ds_write/thread.
// Group mapping rt=bid&15 -> 16 blocks share an XCD (runtime-verified via
// HW_REG_XCC_ID; agent-scope fallback else). Barrier: per-group monotonic ctr,
// tid0 arrive (need=16t), relaxed RMW polls, s_sleep(1) in all spins.
// Step: stage x -> sync(a) -> issue x-prefetch(t+1) -> x-MFMA -> poll -> sync
//       -> h-load/stage -> sync(b) -> h-MFMA -> act -> h-store -> vmcnt(0)
//       -> sync(c) -> arrive.
// ---------------------------------------------------------------------------
__global__ __launch_bounds__(NTH, 2) void lstm_main(
    const float* __restrict__ x, const short* __restrict__ Wb_hi,
    const short* __restrict__ Wb_lo, const float* __restrict__ bp,
    short* __restrict__ hp, unsigned* __restrict__ bar)
{
    __shared__ short Xlds[2][ROWS][XSTR];   // hi/lo planes, x part
    __shared__ short Hlds[ROWS][HSTR];      // plain bf16 h
    __shared__ unsigned mode_sh;

    const int tid = threadIdx.x;
    const int bid = blockIdx.x;
    const int rt = bid & 15;                // row-group (XCD-local mapping)
    const int ct = bid >> 4;
    const int r0 = rt * ROWS;
    const int n0 = ct * COLS;
    const int wv = tid >> 6;                // wave 0..7
    const int l  = tid & 63;
    const int lane16 = l & 15;
    const int lq = l >> 4;                  // k-group 0..3

    // ---- init: publish XCC_ID, grid barrier, per-group locality verdict ----
    if (tid == 0) {
        unsigned xcc;
        asm volatile("s_getreg_b32 %0, hwreg(HW_REG_XCC_ID)" : "=s"(xcc));
        __hip_atomic_store(bar + 640 + bid, xcc, __ATOMIC_RELAXED, __HIP_MEMORY_SCOPE_AGENT);
        asm volatile("s_waitcnt vmcnt(0)" ::: "memory");
        __hip_atomic_fetch_add(bar + 896, 1u, __ATOMIC_RELAXED, __HIP_MEMORY_SCOPE_AGENT);
        for (;;) {
            unsigned v = __hip_atomic_fetch_add(bar + 896, 0u, __ATOMIC_RELAXED,
                                                __HIP_MEMORY_SCOPE_AGENT);
            if (v >= 256u) break;
            __builtin_amdgcn_s_sleep(4);
        }
        unsigned ok = 1;
        for (int k2 = 0; k2 < 16; ++k2) {
            unsigned other = __hip_atomic_load(bar + 640 + rt + 16 * k2,
                                               __ATOMIC_RELAXED, __HIP_MEMORY_SCOPE_AGENT);
            ok &= (other == xcc) ? 1u : 0u;
        }
        mode_sh = ok;
    }
    __syncthreads();
    const bool local_mode = (mode_sh != 0);

    // ---- W fragments to registers, once ----
    s16x8 wh[NKT], wl[NKT];
    {
        const size_t colbase = (size_t)(n0 + wv * 16 + lane16) * KTOT;
        #pragma unroll
        for (int kt = 0; kt < NKT; ++kt) {
            wh[kt] = *(const s16x8*)(Wb_hi + colbase + kt * 32 + lq * 8);
            wl[kt] = *(const s16x8*)(Wb_lo + colbase + kt * 32 + lq * 8);
        }
    }

    const float4 bias = *(const float4*)(bp + n0 + wv * 16 + 4 * lq);
    const int unit_g = (n0 >> 2) + wv * 4 + lq;

    const int srow = tid >> 5;              // staging row 0..15
    const int sl = tid & 31;                // 0..31

    unsigned* ctr = bar + rt * 32;          // 128B-padded per row-group

    float creg = 0.f;

    // x prologue prefetch (t=0)
    float4 xv0, xv1;
    {
        const float* xr = x + (size_t)(r0 + srow) * (SEQL * DIN);
        xv0 = *(const float4*)(xr + 4 * sl);
        xv1 = *(const float4*)(xr + 4 * sl + 128);
    }

    for (int t = 0; t < SEQL; ++t) {
        // ---- pin W frags in registers (no-op asm; blocks rematerialization) ----
        asm volatile("" : "+v"(wh[0]),"+v"(wh[1]),"+v"(wh[2]),"+v"(wh[3]),"+v"(wh[4]),"+v"(wh[5]),"+v"(wh[6]),"+v"(wh[7]),"+v"(wh[8]),"+v"(wh[9]),"+v"(wh[10]),"+v"(wh[11]));
        asm volatile("" : "+v"(wh[12]),"+v"(wh[13]),"+v"(wh[14]),"+v"(wh[15]),"+v"(wh[16]),"+v"(wh[17]),"+v"(wh[18]),"+v"(wh[19]),"+v"(wh[20]),"+v"(wh[21]),"+v"(wh[22]),"+v"(wh[23]));
        asm volatile("" : "+v"(wl[0]),"+v"(wl[1]),"+v"(wl[2]),"+v"(wl[3]),"+v"(wl[4]),"+v"(wl[5]),"+v"(wl[6]),"+v"(wl[7]),"+v"(wl[8]),"+v"(wl[9]),"+v"(wl[10]),"+v"(wl[11]));
        asm volatile("" : "+v"(wl[12]),"+v"(wl[13]),"+v"(wl[14]),"+v"(wl[15]),"+v"(wl[16]),"+v"(wl[17]),"+v"(wl[18]),"+v"(wl[19]),"+v"(wl[20]),"+v"(wl[21]),"+v"(wl[22]),"+v"(wl[23]));

        const short* __restrict__ hin = hp + (size_t)(t & 1) * (BATCH * DH);
        short* __restrict__ hout      = hp + (size_t)((t + 1) & 1) * (BATCH * DH);

        // ---- stage x_t (prefetched regs) -> LDS x planes ----
        {
            float4 v = xv0; int k0 = 4 * sl;
            #pragma unroll
            for (int i = 0; i < 2; ++i) {
                short h0b = bf16_rne(v.x), h1b = bf16_rne(v.y);
                short h2b = bf16_rne(v.z), h3b = bf16_rne(v.w);
                s16x4 hi4 = { h0b, h1b, h2b, h3b };
                s16x4 lo4 = { bf16_rne(v.x - bf16_to_f32(h0b)),
                              bf16_rne(v.y - bf16_to_f32(h1b)),
                              bf16_rne(v.z - bf16_to_f32(h2b)),
                              bf16_rne(v.w - bf16_to_f32(h3b)) };
                *(s16x4*)(&Xlds[0][srow][k0]) = hi4;
                *(s16x4*)(&Xlds[1][srow][k0]) = lo4;
                v = xv1; k0 = 4 * sl + 128;
            }
        }
        __syncthreads();   // (a) x staged; xv regs free

        // ---- issue x-prefetch for t+1: latency hides under the whole step ----
        {
            int tn = (t + 1 < SEQL) ? t + 1 : SEQL - 1;
            const float* xr = x + (size_t)(r0 + srow) * (SEQL * DIN) + (size_t)tn * DIN;
            xv0 = *(const float4*)(xr + 4 * sl);
            xv1 = *(const float4*)(xr + 4 * sl + 128);
        }

        // ---- x-part MFMA: 8 k-tiles x 3 (overlaps other blocks' arrivals) ----
        f32x4 acc0 = {0.f, 0.f, 0.f, 0.f};
        f32x4 acc1 = {0.f, 0.f, 0.f, 0.f};
        {
            const short* ax_hi = &Xlds[0][lane16][lq * 8];
            const short* ax_lo = &Xlds[1][lane16][lq * 8];
            #pragma unroll
            for (int kt = 0; kt < 8; ++kt) {
                s16x8 a_hi = *(const s16x8*)(ax_hi + kt * 32);
                s16x8 a_lo = *(const s16x8*)(ax_lo + kt * 32);
                if (kt & 1) {
                    acc1 = __builtin_amdgcn_mfma_f32_16x16x32_bf16(wh[kt], a_hi, acc1, 0, 0, 0);
                    acc1 = __builtin_amdgcn_mfma_f32_16x16x32_bf16(wl[kt], a_hi, acc1, 0, 0, 0);
                    acc1 = __builtin_amdgcn_mfma_f32_16x16x32_bf16(wh[kt], a_lo, acc1, 0, 0, 0);
                } else {
                    acc0 = __builtin_amdgcn_mfma_f32_16x16x32_bf16(wh[kt], a_hi, acc0, 0, 0, 0);
                    acc0 = __builtin_amdgcn_mfma_f32_16x16x32_bf16(wl[kt], a_hi, acc0, 0, 0, 0);
                    acc0 = __builtin_amdgcn_mfma_f32_16x16x32_bf16(wh[kt], a_lo, acc0, 0, 0, 0);
                }
            }
        }

        // ---- wait: h_{t-1} ready (ctr >= 16*t) ----
        if (tid == 0) {
            const unsigned need = 16u * (unsigned)t;
            if (local_mode) {
                for (;;) {
                    unsigned v = __hip_atomic_fetch_add(ctr, 0u, __ATOMIC_RELAXED,
                                                        __HIP_MEMORY_SCOPE_WORKGROUP);
                    if (v >= need) break;
                    __builtin_amdgcn_s_sleep(1);
                }
            } else {
                for (;;) {
                    unsigned v = __hip_atomic_fetch_add(ctr, 0u, __ATOMIC_RELAXED,
                                                        __HIP_MEMORY_SCOPE_AGENT);
                    if (v >= need) break;
                    __builtin_amdgcn_s_sleep(1);
                }
            }
        }
        __syncthreads();   // release: h data visible at this group's coherence point

        // ---- h load: 2x dwordx4 per thread (32B of row srow) ----
        {
            u32x4 hv0, hv1;
            const short* hrow = hin + (size_t)(r0 + srow) * DH + sl * 16;
            if (local_mode) {
                asm volatile("global_load_dwordx4 %0, %2, off sc0\n\t"
                             "global_load_dwordx4 %1, %3, off sc0"
                             : "=&v"(hv0), "=&v"(hv1)
                             : "v"(hrow), "v"(hrow + 8));
            } else {
                asm volatile("global_load_dwordx4 %0, %2, off sc0 sc1\n\t"
                             "global_load_dwordx4 %1, %3, off sc0 sc1"
                             : "=&v"(hv0), "=&v"(hv1)
                             : "v"(hrow), "v"(hrow + 8));
            }
            asm volatile("s_waitcnt vmcnt(0)" ::: "memory");
            __builtin_amdgcn_sched_barrier(0);
            *(u32x4*)(&Hlds[srow][sl * 16])     = hv0;
            *(u32x4*)(&Hlds[srow][sl * 16 + 8]) = hv1;
        }
        __syncthreads();   // (b) h staged

        // ---- h-part MFMA: 16 k-tiles x 2 ----
        {
            const short* ah = &Hlds[lane16][lq * 8];
            #pragma unroll
            for (int kt = 8; kt < NKT; ++kt) {
                const int ko = (kt - 8) * 32;
                s16x8 a = *(const s16x8*)(ah + ko);
                if (kt & 1) {
                    acc1 = __builtin_amdgcn_mfma_f32_16x16x32_bf16(wh[kt], a, acc1, 0, 0, 0);
                    acc1 = __builtin_amdgcn_mfma_f32_16x16x32_bf16(wl[kt], a, acc1, 0, 0, 0);
                } else {
                    acc0 = __builtin_amdgcn_mfma_f32_16x16x32_bf16(wh[kt], a, acc0, 0, 0, 0);
                    acc0 = __builtin_amdgcn_mfma_f32_16x16x32_bf16(wl[kt], a, acc0, 0, 0, 0);
                }
            }
        }

        float zg = acc0.x + acc1.x + bias.x;
        float zi = acc0.y + acc1.y + bias.y;
        float zf = acc0.z + acc1.z + bias.z;
        float zo = acc0.w + acc1.w + bias.w;

        float gv = fast_sigmoid(zg);   // sigmoid on g (reference quirk)
        float iv = fast_tanh(zi);
        float fv = fast_tanh(zf);
        float ov = fast_tanh(zo);
        creg = gv * iv + creg * fv;
        float hv = fast_tanh(creg) * ov;

        // ---- store h (plain bf16) ----
        {
            short hb = bf16_rne(hv);
            short* dst = hout + (size_t)(r0 + lane16) * DH + unit_g;
            if (local_mode) {
                *dst = hb;                                  // plain store -> XCD L2
            } else {
                asm volatile("global_store_short %0, %1, off sc0 sc1"
                             :: "v"(dst), "v"((unsigned)(unsigned short)hb) : "memory");
            }
        }

        asm volatile("s_waitcnt vmcnt(0)" ::: "memory");   // h stores + x-prefetch drained
        __syncthreads();                                   // (c) all waves drained
        // ---- arrive ----
        if (tid == 0) {
            if (local_mode)
                __hip_atomic_fetch_add(ctr, 1u, __ATOMIC_RELAXED, __HIP_MEMORY_SCOPE_WORKGROUP);
            else
                __hip_atomic_fetch_add(ctr, 1u, __ATOMIC_RELAXED, __HIP_MEMORY_SCOPE_AGENT);
        }
    }
}

// ---------------------------------------------------------------------------
// Final projection + softmax. h is plain bf16, linear layout.
// ---------------------------------------------------------------------------
__global__ __launch_bounds__(256) void proj_softmax(
    const short* __restrict__ h, const float* __restrict__ Wph,
    const float* __restrict__ bP, float* __restrict__ out)
{
    __shared__ float red[256];
    const int r = blockIdx.x;
    const int tid = threadIdx.x;
    float a0 = 0.f, a1 = 0.f, a2 = 0.f, a3 = 0.f;
    const short* hr = h + (size_t)r * DH;
    for (int k = 0; k < DH; ++k) {
        float hvv = bf16_to_f32(hr[k]);
        const float* w = Wph + (size_t)k * NCLS;
        a0 += hvv * w[tid];
        a1 += hvv * w[tid + 256];
        a2 += hvv * w[tid + 512];
        a3 += hvv * w[tid + 768];
    }
    a0 += bP[tid]; a1 += bP[tid + 256]; a2 += bP[tid + 512]; a3 += bP[tid + 768];

    float m = fmaxf(fmaxf(a0, a1), fmaxf(a2, a3));
    red[tid] = m; __syncthreads();
    for (int s = 128; s > 0; s >>= 1) {
        if (tid < s) red[tid] = fmaxf(red[tid], red[tid + s]);
        __syncthreads();
    }
    m = red[0];
    __syncthreads();

    float e0 = expf(a0 - m), e1 = expf(a1 - m), e2 = expf(a2 - m), e3 = expf(a3 - m);
    red[tid] = e0 + e1 + e2 + e3; __syncthreads();
    for (int s = 128; s > 0; s >>= 1) {
        if (tid < s) red[tid] += red[tid + s];
        __syncthreads();
    }
    const float inv = 1.0f / red[0];

    float* o = out + (size_t)r * NCLS;
    o[tid]       = e0 * inv;
    o[tid + 256] = e1 * inv;
    o[tid + 512] = e2 * inv;
    o[tid + 768] = e3 * inv;
}

// ---------------------------------------------------------------------------
extern "C" void kernel_launch(void* const* d_in, const int* in_sizes, int n_in,
                              void* d_out, int out_size, void* d_ws, size_t ws_size,
                              hipStream_t stream)
{
    const float* x   = (const float*)d_in[0];
    const float* Wgx = (const float*)d_in[1];
    const float* Wgh = (const float*)d_in[2];
    const float* bg  = (const float*)d_in[3];
    const float* Wix = (const float*)d_in[4];
    const float* Wih = (const float*)d_in[5];
    const float* bi  = (const float*)d_in[6];
    const float* Wfx = (const float*)d_in[7];
    const float* Wfh = (const float*)d_in[8];
    const float* bf  = (const float*)d_in[9];
    const float* Wox = (const float*)d_in[10];
    const float* Woh = (const float*)d_in[11];
    const float* bo  = (const float*)d_in[12];
    const float* Wph = (const float*)d_in[13];
    const float* bP  = (const float*)d_in[14];

    char* ws = (char*)d_ws;
    short* Wb_hi   = (short*)ws;                             // [2048][768] bf16
    short* Wb_lo   = Wb_hi + (size_t)NG * KTOT;              // [2048][768] bf16
    float* bp      = (float*)(Wb_lo + (size_t)NG * KTOT);    // [2048]
    short* hp      = (short*)(bp + NG);                      // [2][256][512] bf16
    unsigned* bar  = (unsigned*)(hp + (size_t)2 * BATCH * DH);

    pack_kernel<<<(KTOT * NG + 255) / 256, 256, 0, stream>>>(
        Wgx, Wgh, Wix, Wih, Wfx, Wfh, Wox, Woh, bg, bi, bf, bo,
        Wb_hi, Wb_lo, bp, (unsigned*)hp, bar);

    void* args[] = {(void*)&x, (void*)&Wb_hi, (void*)&Wb_lo, (void*)&bp,
                    (void*)&hp, (void*)&bar};
    hipLaunchCooperativeKernel((void*)lstm_main, dim3(256), dim3(NTH), args,
                               0, stream);

    // 512 steps -> final h is in parity 0 (hp base)
    proj_softmax<<<BATCH, 256, 0, stream>>>(hp, Wph, bP, (float*)d_out);
}